// Round 7
// baseline (212.738 us; speedup 1.0000x reference)
//
#include <hip/hip_runtime.h>

#define RTOT 12960      // 4 * 3240 rows
#define PAIRS 3240
#define NB_VAR 81
#define HID 256
#define EPS 1e-5f
#define NBLK 405        // 405 blocks x 32 rows = 12960 exactly; <=512 co-resident at (256,2)
#define NTHR 256

using bf8   = __attribute__((ext_vector_type(8))) short;
using f32x4 = __attribute__((ext_vector_type(4))) float;

__device__ inline ushort f2bf(float f) {
    union { float f; unsigned u; } c; c.f = f;
    unsigned u = c.u + 0x7fffu + ((c.u >> 16) & 1u);
    return (ushort)(u >> 16);
}
__device__ inline float bf2f(ushort h) {
    union { unsigned u; float f; } c; c.u = (unsigned)h << 16;
    return c.f;
}
__device__ inline unsigned pk2(float a, float b) {
    return (unsigned)f2bf(a) | ((unsigned)f2bf(b) << 16);
}
// upper-tri pair from linear index p (0..3239): off(i) = (161*i - i*i)/2
__device__ inline int2 pair_of(int p) {
    int i = (int)((161.0 - sqrt(25921.0 - 8.0 * (double)p)) * 0.5);
    if (i < 0) i = 0;
    while ((161 * (i + 1) - (i + 1) * (i + 1)) / 2 <= p) i++;
    while ((161 * i - i * i) / 2 > p) i--;
    int j = i + 1 + (p - (161 * i - i * i) / 2);
    return make_int2(i, j);
}

struct KP {
    const float *x, *w_in, *b_in, *g1, *beta1, *w1, *bias1, *g2, *beta2,
                *w2, *bias2, *fg, *fbeta, *w_out, *b_out;
    float *out;
    ushort *buf0, *buf1, *buf2, *wbf;
    float *stats;   // 5 slots x 512
    int   *c;       // 8 sync counters (memset to 0 each launch)
};

// ---- sync: counter-only (no cache maintenance) unless fence=true (phase 0 weight publish) ----
__device__ __forceinline__ void syncg(int* c, bool fence) {
    __syncthreads();                        // drains vmem (compiler emits vmcnt(0) before s_barrier)
    if (threadIdx.x == 0) {
        if (fence) __threadfence();         // writeback L2 (publishes converted weights)
        __hip_atomic_fetch_add(c, 1, __ATOMIC_RELAXED, __HIP_MEMORY_SCOPE_AGENT);
        while (__hip_atomic_load(c, __ATOMIC_RELAXED, __HIP_MEMORY_SCOPE_AGENT) < NBLK)
            __builtin_amdgcn_s_sleep(2);
        if (fence) __threadfence();         // acquire side: invalidate stale clean lines
    }
    __syncthreads();
}

// ---- BN coefficients from finalized stats (agent-scope atomic loads bypass L1) ----
__device__ __forceinline__ void coeffs(float* st, const float* g, const float* beta,
                                       float* sS, float* sT) {
    int tid = threadIdx.x;
    float s = __hip_atomic_load(st + tid,       __ATOMIC_RELAXED, __HIP_MEMORY_SCOPE_AGENT);
    float q = __hip_atomic_load(st + HID + tid, __ATOMIC_RELAXED, __HIP_MEMORY_SCOPE_AGENT);
    float m = s * (1.f / RTOT);
    float v = q * (1.f / RTOT) - m * m;
    float sc = g[tid] * rsqrtf(v + EPS);
    sS[tid] = sc;
    sT[tid] = fmaf(-m, sc, beta[tid]);
    __syncthreads();
}

// ---- A-fragment: 8 bf16 from own row, BN+ReLU in registers, repack bf16 ----
__device__ __forceinline__ bf8 ldA(const ushort* xr, int kst,
                                   const float* sS, const float* sT) {
    float4 s0 = *(const float4*)&sS[kst], s1 = *(const float4*)&sS[kst + 4];
    float4 t0 = *(const float4*)&sT[kst], t1 = *(const float4*)&sT[kst + 4];
    ushort xv[8];
    *(uint4*)xv = *(const uint4*)(xr + kst);
    unsigned pk[4];
    pk[0] = pk2(fmaxf(fmaf(bf2f(xv[0]), s0.x, t0.x), 0.f),
                fmaxf(fmaf(bf2f(xv[1]), s0.y, t0.y), 0.f));
    pk[1] = pk2(fmaxf(fmaf(bf2f(xv[2]), s0.z, t0.z), 0.f),
                fmaxf(fmaf(bf2f(xv[3]), s0.w, t0.w), 0.f));
    pk[2] = pk2(fmaxf(fmaf(bf2f(xv[4]), s1.x, t1.x), 0.f),
                fmaxf(fmaf(bf2f(xv[5]), s1.y, t1.y), 0.f));
    pk[3] = pk2(fmaxf(fmaf(bf2f(xv[6]), s1.z, t1.z), 0.f),
                fmaxf(fmaf(bf2f(xv[7]), s1.w, t1.w), 0.f));
    return *(bf8*)pk;
}

// ---- one 256->256 layer for this block's 32 rows; barrier-free; B from global ----
__device__ __forceinline__ void layer(const ushort* __restrict__ X,
        const ushort* __restrict__ Wb, const float* __restrict__ bias,
        const ushort* __restrict__ res, ushort* __restrict__ Y,
        float* __restrict__ stout, const float* sS, const float* sT, int R0) {
    int tid = threadIdx.x, lane = tid & 63, wid = tid >> 6;
    int r16 = lane & 15, kq = lane >> 4;
    int col0 = wid * 64;
    const ushort* xr0 = X + (size_t)(R0 + r16) * HID;
    const ushort* xr1 = X + (size_t)(R0 + 16 + r16) * HID;

    f32x4 acc[2][4] = {};
#pragma unroll
    for (int kk = 0; kk < 8; kk++) {
        int kst = kk * 32 + kq * 8;
        bf8 af0 = ldA(xr0, kst, sS, sT);
        bf8 af1 = ldA(xr1, kst, sS, sT);
        bf8 bfr[4];
#pragma unroll
        for (int n = 0; n < 4; n++)
            bfr[n] = *(const bf8*)(Wb + (size_t)(col0 + n * 16 + r16) * HID + kst);
#pragma unroll
        for (int n = 0; n < 4; n++) {
            acc[0][n] = __builtin_amdgcn_mfma_f32_16x16x32_bf16(af0, bfr[n], acc[0][n], 0, 0, 0);
            acc[1][n] = __builtin_amdgcn_mfma_f32_16x16x32_bf16(af1, bfr[n], acc[1][n], 0, 0, 0);
        }
    }

#pragma unroll
    for (int n = 0; n < 4; n++) {
        int col = col0 + n * 16 + r16;
        float bv = bias[col];
        float cs = 0.f, cq = 0.f;
#pragma unroll
        for (int m = 0; m < 2; m++) {
#pragma unroll
            for (int i = 0; i < 4; i++) {
                int r = R0 + m * 16 + kq * 4 + i;
                float v = acc[m][n][i] + bv;
                if (res) v += bf2f(res[(size_t)r * HID + col]);
                Y[(size_t)r * HID + col] = f2bf(v);
                cs += v; cq += v * v;
            }
        }
        cs += __shfl_xor(cs, 16); cq += __shfl_xor(cq, 16);
        cs += __shfl_xor(cs, 32); cq += __shfl_xor(cq, 32);
        if (lane < 16) {
            atomicAdd(&stout[col0 + n * 16 + lane], cs);
            atomicAdd(&stout[HID + col0 + n * 16 + lane], cq);
        }
    }
}

// ---- the fused persistent kernel ----
__global__ __launch_bounds__(NTHR, 2) void fused(KP p) {
    __shared__ float sS[HID], sT[HID];
    __shared__ float feat[32][4];
    __shared__ int2 pairs_s[32];

    int tid = threadIdx.x;
    int b = blockIdx.x;
    int R0 = b * 32;
    int gtid = b * NTHR + tid;

    // ---- phase 0a: weight conversion fp32->bf16 (grid-strided) ----
    for (int i = gtid; i < 262144 + 81 * 256; i += NBLK * NTHR) {
        float v;
        if (i < 131072)      v = p.w1[i];
        else if (i < 262144) v = p.w2[i - 131072];
        else                 v = p.w_out[i - 262144];
        p.wbf[i] = f2bf(v);
    }
    // ---- phase 0b: zero diagonal blocks of out ----
    for (int i = gtid; i < 4 * NB_VAR * 81; i += NBLK * NTHR) {
        int bb = i / (NB_VAR * 81);
        int rem = i - bb * (NB_VAR * 81);
        int ii = rem / 81, t = rem - ii * 81;
        p.out[((size_t)(bb * NB_VAR + ii) * NB_VAR + ii) * 81 + t] = 0.f;
    }
    // ---- phase 0c: input projection for own 32 rows + stats0 ----
    if (tid < 32) {
        int r = R0 + tid;
        int bb = r / PAIRS, pp = r - bb * PAIRS;
        int2 ij = pair_of(pp);
        pairs_s[tid] = ij;
        const float* xb = p.x + bb * NB_VAR * 2;
        feat[tid][0] = xb[ij.x * 2 + 0];
        feat[tid][1] = xb[ij.x * 2 + 1];
        feat[tid][2] = xb[ij.y * 2 + 0];
        feat[tid][3] = xb[ij.y * 2 + 1];
    }
    __syncthreads();
    {
        float4 w = ((const float4*)p.w_in)[tid];
        float bi = p.b_in[tid];
        float s = 0.f, s2 = 0.f;
        for (int t = 0; t < 32; t++) {
            float v = fmaf(feat[t][0], w.x, fmaf(feat[t][1], w.y,
                      fmaf(feat[t][2], w.z, fmaf(feat[t][3], w.w, bi))));
            v = fmaxf(v, 0.f);
            p.buf0[(size_t)(R0 + t) * HID + tid] = f2bf(v);
            s += v; s2 += v * v;
        }
        atomicAdd(&p.stats[tid], s);
        atomicAdd(&p.stats[HID + tid], s2);
    }
    syncg(p.c + 0, true);   // publishes weights (one-time fence pair)

    // ---- layers 1-4: stats-only syncs, activations stay block-local/L2-warm ----
    coeffs(p.stats + 0 * 512, p.g1, p.beta1, sS, sT);
    layer(p.buf0, p.wbf + 0 * 65536, p.bias1, nullptr, p.buf1, p.stats + 1 * 512, sS, sT, R0);
    syncg(p.c + 1, false);
    coeffs(p.stats + 1 * 512, p.g2, p.beta2, sS, sT);
    layer(p.buf1, p.wbf + 2 * 65536, p.bias2, p.buf0, p.buf2, p.stats + 2 * 512, sS, sT, R0);
    syncg(p.c + 2, false);
    coeffs(p.stats + 2 * 512, p.g1 + HID, p.beta1 + HID, sS, sT);
    layer(p.buf2, p.wbf + 1 * 65536, p.bias1 + HID, nullptr, p.buf1, p.stats + 3 * 512, sS, sT, R0);
    syncg(p.c + 3, false);
    coeffs(p.stats + 3 * 512, p.g2 + HID, p.beta2 + HID, sS, sT);
    layer(p.buf1, p.wbf + 3 * 65536, p.bias2 + HID, p.buf2, p.buf0, p.stats + 4 * 512, sS, sT, R0);
    syncg(p.c + 4, false);

    // ---- final: BN+ReLU + W_out (81 cols) + symmetric scatter, own 32 rows ----
    coeffs(p.stats + 4 * 512, p.fg, p.fbeta, sS, sT);
    {
        int lane = tid & 63, wid = tid >> 6;
        int r16 = lane & 15, kq = lane >> 4;
        const ushort* xr0 = p.buf0 + (size_t)(R0 + r16) * HID;
        const ushort* xr1 = p.buf0 + (size_t)(R0 + 16 + r16) * HID;
        const ushort* Wo = p.wbf + 4 * 65536;
        for (int cf = wid; cf < 6; cf += 4) {
            int t = cf * 16 + r16;
            bool ok = t < 81;
            int tcl = ok ? t : 80;
            f32x4 acc[2] = {};
#pragma unroll
            for (int kk = 0; kk < 8; kk++) {
                int kst = kk * 32 + kq * 8;
                bf8 af0 = ldA(xr0, kst, sS, sT);
                bf8 af1 = ldA(xr1, kst, sS, sT);
                bf8 bv = *(const bf8*)(Wo + (size_t)tcl * HID + kst);
                acc[0] = __builtin_amdgcn_mfma_f32_16x16x32_bf16(af0, bv, acc[0], 0, 0, 0);
                acc[1] = __builtin_amdgcn_mfma_f32_16x16x32_bf16(af1, bv, acc[1], 0, 0, 0);
            }
            if (ok) {
                int gi = t / 9, gj = t - gi * 9;
                int ttr = gj * 9 + gi;
                float bb = p.b_out[t];
#pragma unroll
                for (int m = 0; m < 2; m++) {
#pragma unroll
                    for (int i = 0; i < 4; i++) {
                        int r = R0 + m * 16 + kq * 4 + i;
                        int2 ij = pairs_s[r - R0];
                        int batch = r / PAIRS;
                        size_t base1 = ((size_t)(batch * NB_VAR + ij.x) * NB_VAR + ij.y) * 81;
                        size_t base2 = ((size_t)(batch * NB_VAR + ij.y) * NB_VAR + ij.x) * 81;
                        float v = acc[m][i] + bb;
                        p.out[base1 + t] = v;
                        p.out[base2 + ttr] = v;
                    }
                }
            }
        }
    }
}

extern "C" void kernel_launch(void* const* d_in, const int* in_sizes, int n_in,
                              void* d_out, int out_size, void* d_ws, size_t ws_size,
                              hipStream_t stream) {
    KP p;
    p.x     = (const float*)d_in[0];
    p.w_in  = (const float*)d_in[1];
    p.b_in  = (const float*)d_in[2];
    p.g1    = (const float*)d_in[3];
    p.beta1 = (const float*)d_in[4];
    p.w1    = (const float*)d_in[5];
    p.bias1 = (const float*)d_in[6];
    p.g2    = (const float*)d_in[7];
    p.beta2 = (const float*)d_in[8];
    p.w2    = (const float*)d_in[9];
    p.bias2 = (const float*)d_in[10];
    p.fg    = (const float*)d_in[11];
    p.fbeta = (const float*)d_in[12];
    p.w_out = (const float*)d_in[13];
    p.b_out = (const float*)d_in[14];
    p.out   = (float*)d_out;

    p.buf0 = (ushort*)d_ws;
    p.buf1 = p.buf0 + (size_t)RTOT * HID;
    p.buf2 = p.buf1 + (size_t)RTOT * HID;
    p.wbf  = p.buf2 + (size_t)RTOT * HID;        // 5*65536 ushort
    p.stats = (float*)(p.wbf + 5 * 65536);       // 5*512 floats
    p.c     = (int*)(p.stats + 5 * 512);         // 8 ints

    hipMemsetAsync(p.stats, 0, 5 * 512 * sizeof(float) + 8 * sizeof(int), stream);
    fused<<<NBLK, NTHR, 0, stream>>>(p);
}

// Round 8
// 173.609 us; speedup vs baseline: 1.2254x; 1.2254x over previous
//
#include <hip/hip_runtime.h>

#define RTOT 12960      // 4 * 3240 rows
#define PAIRS 3240
#define NB_VAR 81
#define HID 256
#define EPS 1e-5f

using bf8   = __attribute__((ext_vector_type(8))) short;
using f32x4 = __attribute__((ext_vector_type(4))) float;

__device__ inline ushort f2bf(float f) {
    union { float f; unsigned u; } c; c.f = f;
    unsigned u = c.u + 0x7fffu + ((c.u >> 16) & 1u);
    return (ushort)(u >> 16);
}
__device__ inline float bf2f(ushort h) {
    union { unsigned u; float f; } c; c.u = (unsigned)h << 16;
    return c.f;
}
__device__ inline unsigned pk2(float a, float b) {
    return (unsigned)f2bf(a) | ((unsigned)f2bf(b) << 16);
}
// upper-tri pair from linear index p (0..3239)
__device__ inline int2 pair_of(int p) {
    int i = (int)((161.0 - sqrt(25921.0 - 8.0 * (double)p)) * 0.5);
    if (i < 0) i = 0;
    while ((161 * (i + 1) - (i + 1) * (i + 1)) / 2 <= p) i++;
    while ((161 * i - i * i) / 2 > p) i--;
    int j = i + 1 + (p - (161 * i - i * i) / 2);
    return make_int2(i, j);
}

// ---- A-fragment: 8 bf16, BN+ReLU in registers, repack bf16 ----
__device__ __forceinline__ bf8 ldA(const ushort* xr, int kst,
                                   const float* sS, const float* sT) {
    float4 s0 = *(const float4*)&sS[kst], s1 = *(const float4*)&sS[kst + 4];
    float4 t0 = *(const float4*)&sT[kst], t1 = *(const float4*)&sT[kst + 4];
    ushort xv[8];
    *(uint4*)xv = *(const uint4*)(xr + kst);
    unsigned pk[4];
    pk[0] = pk2(fmaxf(fmaf(bf2f(xv[0]), s0.x, t0.x), 0.f),
                fmaxf(fmaf(bf2f(xv[1]), s0.y, t0.y), 0.f));
    pk[1] = pk2(fmaxf(fmaf(bf2f(xv[2]), s0.z, t0.z), 0.f),
                fmaxf(fmaf(bf2f(xv[3]), s0.w, t0.w), 0.f));
    pk[2] = pk2(fmaxf(fmaf(bf2f(xv[4]), s1.x, t1.x), 0.f),
                fmaxf(fmaf(bf2f(xv[5]), s1.y, t1.y), 0.f));
    pk[3] = pk2(fmaxf(fmaf(bf2f(xv[6]), s1.z, t1.z), 0.f),
                fmaxf(fmaf(bf2f(xv[7]), s1.w, t1.w), 0.f));
    return *(bf8*)pk;
}

// ---------------- init: weights->bf16, pairs, zero out-diag, input proj + stats0 ----------------
__global__ __launch_bounds__(256) void k_init(
        const float* __restrict__ x, const float* __restrict__ w_in,
        const float* __restrict__ b_in,
        const float* __restrict__ w1, const float* __restrict__ w2,
        const float* __restrict__ w_out, ushort* __restrict__ wbf,
        int2* __restrict__ pairs, float* __restrict__ out,
        ushort* __restrict__ h0, float* __restrict__ st) {
    __shared__ float feat[32][4];
    int tid = threadIdx.x;
    int gtid = blockIdx.x * 256 + tid;

    for (int i = gtid; i < 262144 + 81 * 256; i += 405 * 256) {
        float v;
        if (i < 131072)      v = w1[i];
        else if (i < 262144) v = w2[i - 131072];
        else                 v = w_out[i - 262144];
        wbf[i] = f2bf(v);
    }
    if (gtid < 4 * NB_VAR * 81) {
        int b = gtid / (NB_VAR * 81);
        int rem = gtid - b * (NB_VAR * 81);
        int i = rem / 81, t = rem - i * 81;
        out[((size_t)(b * NB_VAR + i) * NB_VAR + i) * 81 + t] = 0.f;
    }

    int r0 = blockIdx.x * 32;
    if (tid < 32) {
        int r = r0 + tid;
        int b = r / PAIRS, p = r - b * PAIRS;
        int2 ij = pair_of(p);
        if (r < PAIRS) pairs[r] = ij;
        const float* xb = x + b * NB_VAR * 2;
        feat[tid][0] = xb[ij.x * 2 + 0];
        feat[tid][1] = xb[ij.x * 2 + 1];
        feat[tid][2] = xb[ij.y * 2 + 0];
        feat[tid][3] = xb[ij.y * 2 + 1];
    }
    __syncthreads();
    float4 w = ((const float4*)w_in)[tid];
    float bi = b_in[tid];
    float s = 0.f, s2 = 0.f;
    for (int t = 0; t < 32; t++) {
        float v = fmaf(feat[t][0], w.x, fmaf(feat[t][1], w.y,
                  fmaf(feat[t][2], w.z, fmaf(feat[t][3], w.w, bi))));
        v = fmaxf(v, 0.f);
        h0[(size_t)(r0 + t) * HID + tid] = f2bf(v);
        s += v; s2 += v * v;
    }
    atomicAdd(&st[tid], s);
    atomicAdd(&st[HID + tid], s2);
}

// ---------------- MFMA GEMM: 32x16 wave tiles, grid (405,4) = 6480 waves ----------------
__global__ __launch_bounds__(256, 5) void k_gemm(
        const ushort* __restrict__ X, const float* __restrict__ stin,
        const float* __restrict__ g, const float* __restrict__ beta,
        const ushort* __restrict__ Wb, const float* __restrict__ bias,
        const ushort* __restrict__ res, ushort* __restrict__ Y,
        float* __restrict__ stout) {
    __shared__ float sS[HID], sT[HID];
    int tid = threadIdx.x;
    {
        float s = stin[tid], q = stin[HID + tid];
        float m = s * (1.f / RTOT);
        float v = q * (1.f / RTOT) - m * m;
        float sc = g[tid] * rsqrtf(v + EPS);
        sS[tid] = sc;
        sT[tid] = fmaf(-m, sc, beta[tid]);
    }
    __syncthreads();

    int R0 = blockIdx.x * 32;                  // 405*32 = 12960 exact, no guards
    int bn0 = blockIdx.y * 64;
    int lane = tid & 63, wid = tid >> 6;
    int r16 = lane & 15, kq = lane >> 4;
    int col0 = bn0 + wid * 16;                 // this wave's 16 cols
    const ushort* xr0 = X + (size_t)(R0 + r16) * HID;
    const ushort* xr1 = X + (size_t)(R0 + 16 + r16) * HID;
    const ushort* wrp = Wb + (size_t)(col0 + r16) * HID;

    f32x4 acc0 = {}, acc1 = {};
#pragma unroll
    for (int kk = 0; kk < 8; kk++) {
        int kst = kk * 32 + kq * 8;
        bf8 af0 = ldA(xr0, kst, sS, sT);
        bf8 af1 = ldA(xr1, kst, sS, sT);
        bf8 bfr = *(const bf8*)(wrp + kst);
        acc0 = __builtin_amdgcn_mfma_f32_16x16x32_bf16(af0, bfr, acc0, 0, 0, 0);
        acc1 = __builtin_amdgcn_mfma_f32_16x16x32_bf16(af1, bfr, acc1, 0, 0, 0);
    }

    int col = col0 + r16;
    float bv = bias[col];
    float cs = 0.f, cq = 0.f;
#pragma unroll
    for (int m = 0; m < 2; m++) {
        const f32x4& a = m ? acc1 : acc0;
#pragma unroll
        for (int i = 0; i < 4; i++) {
            int r = R0 + m * 16 + kq * 4 + i;
            float v = a[i] + bv;
            if (res) v += bf2f(res[(size_t)r * HID + col]);
            Y[(size_t)r * HID + col] = f2bf(v);
            cs += v; cq += v * v;
        }
    }
    cs += __shfl_xor(cs, 16); cq += __shfl_xor(cq, 16);
    cs += __shfl_xor(cs, 32); cq += __shfl_xor(cq, 32);
    if (lane < 16) {
        atomicAdd(&stout[col0 + lane], cs);
        atomicAdd(&stout[HID + col0 + lane], cq);
    }
}

// ---------------- final GEMM (81 cols) + symmetric scatter, grid (405,2) ----------------
__global__ __launch_bounds__(256, 4) void k_gout(
        const ushort* __restrict__ X, const float* __restrict__ stin,
        const float* __restrict__ g, const float* __restrict__ beta,
        const ushort* __restrict__ Wb, const float* __restrict__ b_out,
        const int2* __restrict__ pairs, float* __restrict__ out) {
    __shared__ float sS[HID], sT[HID];
    int tid = threadIdx.x;
    {
        float s = stin[tid], q = stin[HID + tid];
        float m = s * (1.f / RTOT);
        float v = q * (1.f / RTOT) - m * m;
        float sc = g[tid] * rsqrtf(v + EPS);
        sS[tid] = sc;
        sT[tid] = fmaf(-m, sc, beta[tid]);
    }
    __syncthreads();

    int R0 = blockIdx.x * 32;
    int bn0 = blockIdx.y * 64;
    int lane = tid & 63, wid = tid >> 6;
    int r16 = lane & 15, kq = lane >> 4;
    int t = bn0 + wid * 16 + r16;
    bool ok = t < 81;
    int tcl = ok ? t : 80;
    const ushort* xr0 = X + (size_t)(R0 + r16) * HID;
    const ushort* xr1 = X + (size_t)(R0 + 16 + r16) * HID;
    const ushort* wrp = Wb + (size_t)tcl * HID;

    f32x4 acc0 = {}, acc1 = {};
#pragma unroll
    for (int kk = 0; kk < 8; kk++) {
        int kst = kk * 32 + kq * 8;
        bf8 af0 = ldA(xr0, kst, sS, sT);
        bf8 af1 = ldA(xr1, kst, sS, sT);
        bf8 bfr = *(const bf8*)(wrp + kst);
        acc0 = __builtin_amdgcn_mfma_f32_16x16x32_bf16(af0, bfr, acc0, 0, 0, 0);
        acc1 = __builtin_amdgcn_mfma_f32_16x16x32_bf16(af1, bfr, acc1, 0, 0, 0);
    }

    if (ok) {
        int gi = t / 9, gj = t - gi * 9;
        int ttr = gj * 9 + gi;
        float bb = b_out[t];
#pragma unroll
        for (int m = 0; m < 2; m++) {
            const f32x4& a = m ? acc1 : acc0;
#pragma unroll
            for (int i = 0; i < 4; i++) {
                int r = R0 + m * 16 + kq * 4 + i;
                int batch = r / PAIRS, p = r - batch * PAIRS;
                int2 ij = pairs[p];
                size_t base1 = ((size_t)(batch * NB_VAR + ij.x) * NB_VAR + ij.y) * 81;
                size_t base2 = ((size_t)(batch * NB_VAR + ij.y) * NB_VAR + ij.x) * 81;
                float v = a[i] + bb;
                out[base1 + t] = v;
                out[base2 + ttr] = v;
            }
        }
    }
}

extern "C" void kernel_launch(void* const* d_in, const int* in_sizes, int n_in,
                              void* d_out, int out_size, void* d_ws, size_t ws_size,
                              hipStream_t stream) {
    const float* x     = (const float*)d_in[0];
    const float* w_in  = (const float*)d_in[1];
    const float* b_in  = (const float*)d_in[2];
    const float* g1    = (const float*)d_in[3];
    const float* beta1 = (const float*)d_in[4];
    const float* w1    = (const float*)d_in[5];
    const float* bias1 = (const float*)d_in[6];
    const float* g2    = (const float*)d_in[7];
    const float* beta2 = (const float*)d_in[8];
    const float* w2    = (const float*)d_in[9];
    const float* bias2 = (const float*)d_in[10];
    const float* fg    = (const float*)d_in[11];
    const float* fbeta = (const float*)d_in[12];
    const float* w_out = (const float*)d_in[13];
    const float* b_out = (const float*)d_in[14];
    float* out = (float*)d_out;

    ushort* buf0 = (ushort*)d_ws;
    ushort* buf1 = buf0 + (size_t)RTOT * HID;
    ushort* buf2 = buf1 + (size_t)RTOT * HID;
    ushort* wbf  = buf2 + (size_t)RTOT * HID;   // 5*65536 elems
    float* stats = (float*)(wbf + 5 * 65536);
    int2*  pairs = (int2*)(stats + 5 * 512);
    // wbf layout: w1_0 @0, w1_1 @65536, w2_0 @131072, w2_1 @196608, w_out @262144

    hipMemsetAsync(stats, 0, 5 * 512 * sizeof(float), stream);
    k_init<<<405, 256, 0, stream>>>(x, w_in, b_in, w1, w2, w_out, wbf,
                                    pairs, out, buf0, stats + 0 * 512);

    dim3 gmid(405, 4);
    dim3 gfin(405, 2);

    k_gemm<<<gmid, 256, 0, stream>>>(buf0, stats + 0 * 512, g1, beta1,
                                     wbf + 0 * 65536, bias1, nullptr, buf1, stats + 1 * 512);
    k_gemm<<<gmid, 256, 0, stream>>>(buf1, stats + 1 * 512, g2, beta2,
                                     wbf + 2 * 65536, bias2, buf0, buf2, stats + 2 * 512);
    k_gemm<<<gmid, 256, 0, stream>>>(buf2, stats + 2 * 512, g1 + HID, beta1 + HID,
                                     wbf + 1 * 65536, bias1 + HID, nullptr, buf1, stats + 3 * 512);
    k_gemm<<<gmid, 256, 0, stream>>>(buf1, stats + 3 * 512, g2 + HID, beta2 + HID,
                                     wbf + 3 * 65536, bias2 + HID, buf2, buf0, stats + 4 * 512);
    k_gout<<<gfin, 256, 0, stream>>>(buf0, stats + 4 * 512, fg, fbeta,
                                     wbf + 4 * 65536, b_out, pairs, out);
}